// Round 4
// baseline (117.974 us; speedup 1.0000x reference)
//
#include <hip/hip_runtime.h>

// Reference collapses algebraically:
//   The graph-refinement feature dim is 1, so LayerNorm over axis -1 gives
//   (y - mean) = 0 and var = 0 EXACTLY -> h = ln_bias[l] for any finite input.
//   => refined = softplus(ln_bias[1,0])  (scalar, = ln 2 since ln_bias = 0)
//   => out[i]  = refined * sigmoid((1 - psi_n[i]) * 50)
//
// Dtype deduction (rounds 0-3): output MUST be f32 (bf16-out failed with both
// input dtypes -> contradiction), inputs are f32 per npz compression math.
// Defensive: a 1-thread sniff kernel checks whether ndeg reads as exact small
// integers in f32 (true f32 data) vs junk-mantissa floats (bf16 pairs), and
// the main kernel branches uniformly on that flag.

__device__ __forceinline__ float bf16_to_f32(unsigned short s) {
    return __uint_as_float(((unsigned int)s) << 16);
}

__global__ void VICTOR_v6_sniff(const float* __restrict__ ndeg,
                                int* __restrict__ flag) {
    if (threadIdx.x == 0 && blockIdx.x == 0) {
        int isf32 = 1;
        #pragma unroll
        for (int j = 0; j < 16; ++j) {
            float v = ndeg[j];   // 64 B read: safe under either dtype
            bool ok = (v >= 1.0f) && (v <= 16384.0f) && (floorf(v) == v);
            if (!ok) isf32 = 0;
        }
        *flag = isf32;
    }
}

__global__ __launch_bounds__(256)
void VICTOR_v6_main(const void* __restrict__ psi_raw,
                    const void* __restrict__ lnb_raw,
                    const int* __restrict__ flag,
                    float* __restrict__ out, int n) {
    int i = blockIdx.x * blockDim.x + threadIdx.x;
    if (i >= n) return;

    const int f32mode = *flag;   // wave-uniform branch
    float lb, x;
    if (f32mode) {
        lb = ((const float*)lnb_raw)[1];
        x  = ((const float*)psi_raw)[i];
    } else {
        lb = bf16_to_f32(((const unsigned short*)lnb_raw)[1]);
        x  = bf16_to_f32(((const unsigned short*)psi_raw)[i]);
    }

    const float refined = fmaxf(lb, 0.0f) + log1pf(expf(-fabsf(lb)));  // softplus
    const float r = refined / (1.0f + expf((x - 1.0f) * 50.0f));       // * sigmoid((1-x)*50)
    out[i] = r;
}

extern "C" void kernel_launch(void* const* d_in, const int* in_sizes, int n_in,
                              void* d_out, int out_size, void* d_ws, size_t ws_size,
                              hipStream_t stream) {
    // setup_inputs() order:
    //  0 R_flat, 1 Z_flat, 2 psi_n, 3 bpol_n, 4 ew, 5 ndeg,
    //  6 coord_tables, 7 field_tables, 8 so2_W, 9 so2_b, 10 om1, 11 W1, 12 b1,
    // 13 om2, 14 W2, 15 b2, 16 mem_W1, 17 mem_b1, 18 mem_W2, 19 mem_b2,
    // 20 pW1, 21 pb1, 22 pW2, 23 pb2, 24 ln_scale, 25 ln_bias, 26 esrc, 27 edst
    const void* psi_raw = d_in[2];
    const void* lnb_raw = d_in[25];
    const float* ndeg_f = (const float*)d_in[5];
    float* out          = (float*)d_out;
    int* flag           = (int*)d_ws;   // d_ws re-poisoned each call; we rewrite it

    const int n = out_size;             // 65536 (NG*NG), the one size we're sure of

    VICTOR_v6_sniff<<<1, 64, 0, stream>>>(ndeg_f, flag);
    VICTOR_v6_main<<<(n + 255) / 256, 256, 0, stream>>>(psi_raw, lnb_raw, flag, out, n);
}

// Round 5
// 117.919 us; speedup vs baseline: 1.0005x; 1.0005x over previous
//
#include <hip/hip_runtime.h>

// Reference collapses algebraically:
//   The graph-refinement feature dim is 1, so LayerNorm over axis -1 gives
//   (y - mean) = 0 and var = 0 EXACTLY -> h = ln_bias[l] for any finite input.
//   => refined = softplus(ln_bias[1,0])  (scalar)
//   => out[i]  = refined * sigmoid((1 - psi_n[i]) * 50)
// Round-4 PASSED (absmax 0.0). dur_us=118 is harness-reset floor (d_ws 256MiB
// 0xAA poison = 45us fillBuffer x2 per iter dominates). This round: fold the
// dtype sniff into the main kernel -> single launch, no d_ws use.
//
// Dtype self-detection (kept for safety; absmax 0.0 confirmed it works but
// not which mode fired): ndeg holds exact small integer degrees >= 1 in its
// true dtype. Read as f32: floorf(v)==v, 1<=v<=16384. If the data were bf16
// pairs, the reassembled f32 has junk mantissa/exponent -> check fails.
// All 64 lanes check the same 16 values -> result is wave-uniform.

__device__ __forceinline__ float bf16_to_f32(unsigned short s) {
    return __uint_as_float(((unsigned int)s) << 16);
}

__global__ __launch_bounds__(256)
void VICTOR_v6_main(const void* __restrict__ psi_raw,
                    const void* __restrict__ lnb_raw,
                    const float* __restrict__ ndeg,
                    float* __restrict__ out, int n) {
    int i = blockIdx.x * blockDim.x + threadIdx.x;
    if (i >= n) return;

    // inline dtype sniff (uniform across all threads; 16 L2-broadcast loads)
    bool isf32 = true;
    #pragma unroll
    for (int j = 0; j < 16; ++j) {
        float v = ndeg[j];
        isf32 = isf32 && (v >= 1.0f) && (v <= 16384.0f) && (floorf(v) == v);
    }

    float lb, x;
    if (isf32) {
        lb = ((const float*)lnb_raw)[1];
        x  = ((const float*)psi_raw)[i];
    } else {
        lb = bf16_to_f32(((const unsigned short*)lnb_raw)[1]);
        x  = bf16_to_f32(((const unsigned short*)psi_raw)[i]);
    }

    const float refined = fmaxf(lb, 0.0f) + log1pf(expf(-fabsf(lb)));  // softplus
    out[i] = refined / (1.0f + expf((x - 1.0f) * 50.0f));              // * sigmoid((1-x)*50)
}

extern "C" void kernel_launch(void* const* d_in, const int* in_sizes, int n_in,
                              void* d_out, int out_size, void* d_ws, size_t ws_size,
                              hipStream_t stream) {
    // setup_inputs() order:
    //  0 R_flat, 1 Z_flat, 2 psi_n, 3 bpol_n, 4 ew, 5 ndeg,
    //  6 coord_tables, 7 field_tables, 8 so2_W, 9 so2_b, 10 om1, 11 W1, 12 b1,
    // 13 om2, 14 W2, 15 b2, 16 mem_W1, 17 mem_b1, 18 mem_W2, 19 mem_b2,
    // 20 pW1, 21 pb1, 22 pW2, 23 pb2, 24 ln_scale, 25 ln_bias, 26 esrc, 27 edst
    const void* psi_raw = d_in[2];
    const void* lnb_raw = d_in[25];
    const float* ndeg_f = (const float*)d_in[5];
    float* out          = (float*)d_out;

    const int n = out_size;   // 65536 (NG*NG)

    VICTOR_v6_main<<<(n + 255) / 256, 256, 0, stream>>>(psi_raw, lnb_raw, ndeg_f, out, n);
}